// Round 8
// baseline (56.303 us; speedup 1.0000x reference)
//
#include <hip/hip_runtime.h>
#include <cmath>

#define CC 16      // concepts
#define BB 256     // batch (rows)
#define KK 8       // classes per concept
#define NN 8192    // background size (columns)
#define TPB 512    // threads per block (8 waves)
#define NH  (NN / 2)         // 4096 columns per half-row block
#define CHUNK 8              // elements per thread
#define NW  (TPB / 64)       // 8 waves
#define MAGICA 0x13572468u
#define MAGICB 0x2468ACEFu

__global__ __launch_bounds__(512) void zero_flags(unsigned* __restrict__ f) {
    f[threadIdx.x] = 0u;     // 512 flags
}

__global__ __launch_bounds__(TPB) void beran_kernel(
    const float* __restrict__ c_p,
    const int*   __restrict__ c_in,
    const float* __restrict__ delta_in,
    const float* __restrict__ bandwidth,
    unsigned*    __restrict__ flg,     // [512] in ws, zeroed per call
    float*       __restrict__ valT,    // [512] in ws
    float*       __restrict__ valH,    // [512] in ws
    float*       __restrict__ out)
{
    constexpr float TOL = 1e-8f + 1e-5f;   // torch.isclose default vs 1.0
    constexpr float EPS = 1e-13f;

    __shared__ float p_lds[CC * KK];       // softmax probs
    __shared__ float sq_lds[CC];           // per-concept sum(p^2)
    __shared__ float w_lds[NH + NH / 8];   // 18 KB padded transpose buffer
    __shared__ float wt[NW], wt2[NW], wl[NW];
    __shared__ float sh_To, sh_Ho;

    const int bid   = blockIdx.x;
    const int row   = bid >> 1;            // batch row
    const int half  = bid & 1;             // which half of the row
    const int part  = bid ^ 1;             // partner block
    const int t     = threadIdx.x;
    const int lane  = t & 63;
    const int wid   = t >> 6;
    const int nbase = half * NH;
    const int n0g   = nbase + t * CHUNK;   // global col of this thread's chunk

    // ---- early prefetch: delta (consumed in xi phase; hides cold miss) ----
    float4 dl0 = *(const float4*)(delta_in + n0g);
    float4 dl1 = *(const float4*)(delta_in + n0g + 4);

    // ---- parallel softmax: one thread per (concept, class), 8-lane groups ----
    if (t < CC * KK) {
        const int c = t >> 3, k = t & 7;
        float v = c_p[((size_t)c * BB + row) * KK + k];
        float m = v;
        #pragma unroll
        for (int d = 1; d < 8; d <<= 1) m = fmaxf(m, __shfl_xor(m, d));
        float e = __expf(v - m);
        float s = e;
        #pragma unroll
        for (int d = 1; d < 8; d <<= 1) s += __shfl_xor(s, d);
        float p = e / s;
        p_lds[t] = p;
        float pp = p * p;
        #pragma unroll
        for (int d = 1; d < 8; d <<= 1) pp += __shfl_xor(pp, d);
        if (k == 0) sq_lds[c] = pp;
    }
    __syncthreads();

    float S = (float)CC;                   // metric = S - 2*dot
    #pragma unroll
    for (int c = 0; c < CC; ++c) S += sq_lds[c];
    const float bw = fminf(fmaxf(bandwidth[0], 0.1f), 10.0f);
    const float inv_bw = 1.0f / bw;

    // ---- pass A (strided n_loc = k*TPB + t): coalesced c_in, broadcast gathers
    #pragma unroll
    for (int k = 0; k < CHUNK; ++k) {
        const int n_loc = k * TPB + t;
        const int4* rowp = (const int4*)(c_in + (size_t)(nbase + n_loc) * CC);
        int4 q0 = rowp[0], q1 = rowp[1], q2 = rowp[2], q3 = rowp[3];
        float dot =
            p_lds[ 0 * KK + q0.x] + p_lds[ 1 * KK + q0.y] +
            p_lds[ 2 * KK + q0.z] + p_lds[ 3 * KK + q0.w] +
            p_lds[ 4 * KK + q1.x] + p_lds[ 5 * KK + q1.y] +
            p_lds[ 6 * KK + q1.z] + p_lds[ 7 * KK + q1.w] +
            p_lds[ 8 * KK + q2.x] + p_lds[ 9 * KK + q2.y] +
            p_lds[10 * KK + q2.z] + p_lds[11 * KK + q2.w] +
            p_lds[12 * KK + q3.x] + p_lds[13 * KK + q3.y] +
            p_lds[14 * KK + q3.z] + p_lds[15 * KK + q3.w];
        w_lds[n_loc + (n_loc >> 3)] = __expf((2.0f * dot - S) * inv_bw);
    }
    __syncthreads();

    // ---- transpose read back: idx(t*8+i) = 9*t + i ----
    float w[CHUNK];
    #pragma unroll
    for (int i = 0; i < CHUNK; ++i) w[i] = w_lds[9 * t + i];

    // ---- scan 1: local inclusive cumsum of raw weights ----
    float incl[CHUNK];
    float run = 0.f;
    #pragma unroll
    for (int i = 0; i < CHUNK; ++i) { run += w[i]; incl[i] = run; }
    float x = run;
    #pragma unroll
    for (int d = 1; d < 64; d <<= 1) {
        float y = __shfl_up(x, d);
        if (lane >= d) x += y;
    }
    if (lane == 63) wt[wid] = x;
    __syncthreads();
    float woff = 0.f, Tl = 0.f;
    #pragma unroll
    for (int ww = 0; ww < NW; ++ww) {
        float v = wt[ww];
        if (ww < wid) woff += v;
        Tl += v;
    }

    // ---- exchange A: half-totals (point-to-point, device scope) ----
    if (t == 0) {
        valT[bid] = Tl;
        __threadfence();
        atomicExch(&flg[bid], MAGICA);
        unsigned f;
        do {
            f = atomicAdd(&flg[part], 0u);
            if (f == 0u) __builtin_amdgcn_s_sleep(1);
        } while (f == 0u);                 // MAGICA or MAGICB both mean ready
        __threadfence();
        sh_To = ((volatile float*)valT)[part];
    }
    __syncthreads();
    const float To = sh_To;
    const float T0 = half ? To : Tl;
    const float T1 = half ? Tl : To;
    const float total = T0 + T1;           // same bits in both halves
    const float base1 = (half ? T0 : 0.f) + woff + (x - run);
    const float inv_s = (total < EPS) ? 0.0f : (1.0f / total);

    // ---- xi (cs = cumsum_raw/total; row-tail cs = 1 +- ulp -> mask fires) ----
    const float del[CHUNK] = {dl0.x, dl0.y, dl0.z, dl0.w, dl1.x, dl1.y, dl1.z, dl1.w};
    float fxi[CHUNK];
    #pragma unroll
    for (int i = 0; i < CHUNK; ++i) {
        float cs = (base1 + incl[i]) * inv_s;   // inclusive cumsum of W
        float Wn = w[i] * inv_s;                // W[n]
        float sh = cs - Wn;                     // exclusive cumsum (shifted)
        bool bad = (fabsf(sh - 1.0f) <= TOL) || (fabsf(cs - 1.0f) <= TOL);
        float xi = bad ? 0.0f : (__logf(1.0f - sh) - __logf(1.0f - cs));
        fxi[i] = del[i] * xi;
    }

    // ---- scan 2: local cumsum of filtered_xi ----
    run = 0.f;
    #pragma unroll
    for (int i = 0; i < CHUNK; ++i) { run += fxi[i]; incl[i] = run; }
    x = run;
    #pragma unroll
    for (int d = 1; d < 64; d <<= 1) {
        float y = __shfl_up(x, d);
        if (lane >= d) x += y;
    }
    if (lane == 63) wt2[wid] = x;
    __syncthreads();
    float woff2 = 0.f, Hl = 0.f;
    #pragma unroll
    for (int ww = 0; ww < NW; ++ww) {
        float v = wt2[ww];
        if (ww < wid) woff2 += v;
        Hl += v;
    }

    // ---- exchange B: fxi-totals ----
    if (t == 0) {
        valH[bid] = Hl;
        __threadfence();
        atomicExch(&flg[bid], MAGICB);
        unsigned f;
        do {
            f = atomicAdd(&flg[part], 0u);
            if (f != MAGICB) __builtin_amdgcn_s_sleep(1);
        } while (f != MAGICB);
        __threadfence();
        sh_Ho = ((volatile float*)valH)[part];
    }
    __syncthreads();
    const float Ho = sh_Ho;
    const float H0 = half ? Ho : Hl;
    const float H1 = half ? Hl : Ho;
    const float base2 = (half ? H0 : 0.f) + woff2 + (x - run);

    // ---- surv_func = exp(-hazards) ----
    float* out0 = out + (size_t)row * NN;
    float sv[CHUNK];
    #pragma unroll
    for (int i = 0; i < CHUNK; ++i) sv[i] = __expf(-(base2 + incl[i]));
    *(float4*)(out0 + n0g)     = make_float4(sv[0], sv[1], sv[2], sv[3]);
    *(float4*)(out0 + n0g + 4) = make_float4(sv[4], sv[5], sv[6], sv[7]);
    if (lane == 63) wl[wid] = sv[CHUNK - 1];
    __syncthreads();

    // ---- surv_steps; s2 telescopes to 1 - surv_last (same bits both halves) ----
    float pv = __shfl_up(sv[CHUNK - 1], 1);
    if (lane == 0) pv = (wid == 0) ? (half ? __expf(-H0) : 1.0f) : wl[wid - 1];
    if (t == 0)    pv = half ? __expf(-H0) : 1.0f;
    const float s2 = 1.0f - __expf(-(H0 + H1));
    const float inv2 = (s2 < EPS) ? 0.0f : (1.0f / s2);
    float st[CHUNK];
    #pragma unroll
    for (int i = 0; i < CHUNK; ++i) {
        st[i] = pv - sv[i];        // steps[0]=1-surv[0]; steps[n]=surv[n-1]-surv[n]
        pv = sv[i];
    }
    float* out1 = out + (size_t)BB * NN + (size_t)row * NN;
    *(float4*)(out1 + n0g)     = make_float4(st[0]*inv2, st[1]*inv2, st[2]*inv2, st[3]*inv2);
    *(float4*)(out1 + n0g + 4) = make_float4(st[4]*inv2, st[5]*inv2, st[6]*inv2, st[7]*inv2);
}

extern "C" void kernel_launch(void* const* d_in, const int* in_sizes, int n_in,
                              void* d_out, int out_size, void* d_ws, size_t ws_size,
                              hipStream_t stream) {
    (void)in_sizes; (void)n_in; (void)out_size; (void)ws_size;
    const float* c_p       = (const float*)d_in[0];
    const int*   c_in      = (const int*)d_in[1];
    const float* delta_in  = (const float*)d_in[2];
    const float* bandwidth = (const float*)d_in[3];
    float*       out       = (float*)d_out;
    unsigned* flg  = (unsigned*)d_ws;                       // 512 flags
    float*    valT = (float*)((char*)d_ws + 2048);          // 512 floats
    float*    valH = (float*)((char*)d_ws + 4096);          // 512 floats
    hipLaunchKernelGGL(zero_flags, dim3(1), dim3(512), 0, stream, flg);
    hipLaunchKernelGGL(beran_kernel, dim3(2 * BB), dim3(TPB), 0, stream,
                       c_p, c_in, delta_in, bandwidth, flg, valT, valH, out);
}

// Round 9
// 22.055 us; speedup vs baseline: 2.5529x; 2.5529x over previous
//
#include <hip/hip_runtime.h>
#include <cmath>

#define CC 16      // concepts
#define BB 256     // batch (rows)
#define KK 8       // classes per concept
#define NN 8192    // background size (columns)
#define TPB 1024
#define CHUNK (NN / TPB)     // 8 elements per thread
#define NWAVES (TPB / 64)    // 16 waves per block
#define NPAIR (CC / 2)       // 8 concept pairs

// ---- pre-pack: row -> 8 bytes of 6-bit pair-gather indices; delta in bit 6 of byte 0
__global__ __launch_bounds__(128) void pack_kernel(const int* __restrict__ c_in,
                                                   const float* __restrict__ delta_in,
                                                   uint2* __restrict__ pk) {
    const int j = blockIdx.x * 128 + threadIdx.x;   // one row per thread
    const int4* row = (const int4*)(c_in + (size_t)j * CC);
    int4 q0 = row[0], q1 = row[1], q2 = row[2], q3 = row[3];
    unsigned d = (delta_in[j] != 0.0f) ? (1u << 6) : 0u;
    unsigned lo = ((unsigned)(q0.x << 3 | q0.y) | d)
                | ((unsigned)(q0.z << 3 | q0.w) << 8)
                | ((unsigned)(q1.x << 3 | q1.y) << 16)
                | ((unsigned)(q1.z << 3 | q1.w) << 24);
    unsigned hi = (unsigned)(q2.x << 3 | q2.y)
                | ((unsigned)(q2.z << 3 | q2.w) << 8)
                | ((unsigned)(q3.x << 3 | q3.y) << 16)
                | ((unsigned)(q3.z << 3 | q3.w) << 24);
    pk[j] = make_uint2(lo, hi);
}

__global__ __launch_bounds__(TPB) void beran_kernel(
    const float* __restrict__ c_p,
    const float* __restrict__ bandwidth,
    const uint2* __restrict__ pk,
    float* __restrict__ out)
{
    constexpr float TOL = 1e-8f + 1e-5f;   // torch.isclose default vs 1.0
    constexpr float EPS = 1e-13f;

    __shared__ float p_lds[CC * KK];       // softmax probs
    __shared__ float sq_lds[CC];           // per-concept sum(p^2)
    __shared__ float T_lds[NPAIR * 64];    // pair tables: T[cp][i0*8+i1]
    __shared__ float wt[NWAVES];           // wave totals, scan 1 (+ steps reduce)
    __shared__ float wt2[NWAVES];          // wave totals, scan 2
    __shared__ float wl[NWAVES];           // per-wave last surv value

    const int b    = blockIdx.x;           // one block per batch row
    const int t    = threadIdx.x;
    const int lane = t & 63;
    const int wid  = t >> 6;
    const int n0   = t * CHUNK;            // contiguous chunk per thread

    // ================= phase 0: issue ALL cold global loads NOW =================
    const uint2* prow = pk + (size_t)t * CHUNK;     // 64 B contiguous per thread
    uint4 A0 = ((const uint4*)prow)[0];             // rows 0,1
    uint4 A1 = ((const uint4*)prow)[1];             // rows 2,3
    uint4 A2 = ((const uint4*)prow)[2];             // rows 4,5
    uint4 A3 = ((const uint4*)prow)[3];             // rows 6,7
    float v_sm = 0.f;
    if (t < CC * KK) v_sm = c_p[((size_t)(t >> 3) * BB + b) * KK + (t & 7)];
    const float bwraw = bandwidth[0];
    __builtin_amdgcn_sched_barrier(0);   // keep the loads issued before softmax code

    // ---- softmax overlaps the in-flight pk misses ----
    if (t < CC * KK) {
        const int k = t & 7;
        float m = v_sm;
        #pragma unroll
        for (int d = 1; d < 8; d <<= 1) m = fmaxf(m, __shfl_xor(m, d));
        float e = __expf(v_sm - m);
        float s = e;
        #pragma unroll
        for (int d = 1; d < 8; d <<= 1) s += __shfl_xor(s, d);
        float p = e / s;
        p_lds[t] = p;
        float pp = p * p;
        #pragma unroll
        for (int d = 1; d < 8; d <<= 1) pp += __shfl_xor(pp, d);
        if (k == 0) sq_lds[t >> 3] = pp;
    }
    __syncthreads();

    // ---- pair tables + S ----
    if (t < NPAIR * 64) {
        const int cp = t >> 6, i = t & 63;
        T_lds[t] = p_lds[(2 * cp) * KK + (i >> 3)] + p_lds[(2 * cp + 1) * KK + (i & 7)];
    }
    float S = (float)CC;                   // metric = S - 2*dot
    #pragma unroll
    for (int c = 0; c < CC; ++c) S += sq_lds[c];
    const float bw = fminf(fmaxf(bwraw, 0.1f), 10.0f);
    const float inv_bw = 1.0f / bw;
    __syncthreads();

    // ---- pass A: 8 table gathers per element (pk already in registers) ----
    const uint2 u[CHUNK] = {
        {A0.x, A0.y}, {A0.z, A0.w}, {A1.x, A1.y}, {A1.z, A1.w},
        {A2.x, A2.y}, {A2.z, A2.w}, {A3.x, A3.y}, {A3.z, A3.w}};
    float w[CHUNK], del[CHUNK];
    #pragma unroll
    for (int i = 0; i < CHUNK; ++i) {
        const unsigned x = u[i].x, y = u[i].y;
        del[i] = (float)((x >> 6) & 1u);
        float dot2 =
            T_lds[  0 + ( x         & 0x3Fu)] +
            T_lds[ 64 + ((x >>  8)  & 0x3Fu)] +
            T_lds[128 + ((x >> 16)  & 0x3Fu)] +
            T_lds[192 + ((x >> 24)  & 0x3Fu)] +
            T_lds[256 + ( y         & 0x3Fu)] +
            T_lds[320 + ((y >>  8)  & 0x3Fu)] +
            T_lds[384 + ((y >> 16)  & 0x3Fu)] +
            T_lds[448 + ((y >> 24)  & 0x3Fu)];
        w[i] = __expf((2.0f * dot2 - S) * inv_bw);
    }

    // ---- scan 1: inclusive cumsum of raw weights ----
    float incl[CHUNK];
    float run = 0.f;
    #pragma unroll
    for (int i = 0; i < CHUNK; ++i) { run += w[i]; incl[i] = run; }
    float x = run;
    #pragma unroll
    for (int d = 1; d < 64; d <<= 1) {
        float y = __shfl_up(x, d);
        if (lane >= d) x += y;
    }
    if (lane == 63) wt[wid] = x;
    __syncthreads();
    float woff = 0.f, total = 0.f;
    #pragma unroll
    for (int ww = 0; ww < NWAVES; ++ww) {
        float v = wt[ww];
        if (ww < wid) woff += v;
        total += v;
    }
    const float base1 = woff + (x - run);           // exclusive offset for this thread
    const float inv_s = (total < EPS) ? 0.0f : (1.0f / total);

    // ---- xi (cs = cumsum_raw/total; tail cs = 1 +- ulp -> isclose mask fires) ----
    float fxi[CHUNK];
    #pragma unroll
    for (int i = 0; i < CHUNK; ++i) {
        float cs = (base1 + incl[i]) * inv_s;       // inclusive cumsum of W
        float Wn = w[i] * inv_s;                    // W[n]
        float sh = cs - Wn;                         // exclusive cumsum (shifted)
        bool bad = (fabsf(sh - 1.0f) <= TOL) || (fabsf(cs - 1.0f) <= TOL);
        float xi = bad ? 0.0f : (__logf(1.0f - sh) - __logf(1.0f - cs));
        fxi[i] = del[i] * xi;
    }

    // ---- scan 2: hazards = cumsum(filtered_xi) ----
    run = 0.f;
    #pragma unroll
    for (int i = 0; i < CHUNK; ++i) { run += fxi[i]; incl[i] = run; }
    x = run;
    #pragma unroll
    for (int d = 1; d < 64; d <<= 1) {
        float y = __shfl_up(x, d);
        if (lane >= d) x += y;
    }
    if (lane == 63) wt2[wid] = x;
    __syncthreads();
    woff = 0.f;
    #pragma unroll
    for (int ww = 0; ww < NWAVES; ++ww) {
        float v = wt2[ww];
        if (ww < wid) woff += v;
    }
    const float base2 = woff + (x - run);

    // ---- surv_func = exp(-hazards) ----
    float* out0 = out + (size_t)b * NN;
    float sv[CHUNK];
    #pragma unroll
    for (int i = 0; i < CHUNK; ++i) sv[i] = __expf(-(base2 + incl[i]));
    *(float4*)(out0 + n0)     = make_float4(sv[0], sv[1], sv[2], sv[3]);
    *(float4*)(out0 + n0 + 4) = make_float4(sv[4], sv[5], sv[6], sv[7]);
    if (lane == 63) wl[wid] = sv[CHUNK - 1];        // wave-boundary surv
    __syncthreads();

    // ---- surv_steps: neighbor surv[n0-1] via shfl + wave boundary ----
    float pv = __shfl_up(sv[CHUNK - 1], 1);         // prev thread's last surv
    if (lane == 0) pv = (wid == 0) ? 1.0f : wl[wid - 1];
    if (t == 0)    pv = 1.0f;
    float st[CHUNK];
    float ls = 0.f;
    #pragma unroll
    for (int i = 0; i < CHUNK; ++i) {
        st[i] = pv - sv[i];        // steps[0]=1-surv[0]; steps[n]=surv[n-1]-surv[n]
        pv = sv[i];
        ls += st[i];
    }
    x = ls;
    #pragma unroll
    for (int d = 1; d < 64; d <<= 1) x += __shfl_xor(x, d);
    if (lane == 0) wt[wid] = x;    // wt reads from scan 1 finished before barriers
    __syncthreads();
    float s2 = 0.f;
    #pragma unroll
    for (int ww = 0; ww < NWAVES; ++ww) s2 += wt[ww];
    const float inv2 = (s2 < EPS) ? 0.0f : (1.0f / s2);
    float* out1 = out + (size_t)BB * NN + (size_t)b * NN;
    *(float4*)(out1 + n0)     = make_float4(st[0]*inv2, st[1]*inv2, st[2]*inv2, st[3]*inv2);
    *(float4*)(out1 + n0 + 4) = make_float4(st[4]*inv2, st[5]*inv2, st[6]*inv2, st[7]*inv2);
}

extern "C" void kernel_launch(void* const* d_in, const int* in_sizes, int n_in,
                              void* d_out, int out_size, void* d_ws, size_t ws_size,
                              hipStream_t stream) {
    (void)in_sizes; (void)n_in; (void)out_size; (void)ws_size;
    const float* c_p       = (const float*)d_in[0];
    const int*   c_in      = (const int*)d_in[1];
    const float* delta_in  = (const float*)d_in[2];
    const float* bandwidth = (const float*)d_in[3];
    float*       out       = (float*)d_out;
    uint2* pk = (uint2*)d_ws;   // 64 KB of the workspace
    hipLaunchKernelGGL(pack_kernel, dim3(NN / 128), dim3(128), 0, stream,
                       c_in, delta_in, pk);
    hipLaunchKernelGGL(beran_kernel, dim3(BB), dim3(TPB), 0, stream,
                       c_p, bandwidth, pk, out);
}